// Round 3
// baseline (937.059 us; speedup 1.0000x reference)
//
#include <hip/hip_runtime.h>
#include <hip/hip_bf16.h>
#include <math.h>

#define B_    16
#define G_    4096
#define M_    128
#define D_    768
#define GI15  0.16431676725154983f   // 0.3^1.5
#define EPS_  1e-12f

// ---------------------------------------------------------------------------
// K0: Gram_u[b][m][m'] = sum_g gto[g,m]*gto[g,m'] (unnormalized GTO basis).
// Diagonal doubles as the per-(b,m) column norm^2 (replaces k_gto_norm).
// 256 blocks: (chunk, b); each accumulates over 256 g's, atomicAdd at end.
// ---------------------------------------------------------------------------
#define NCH  16
#define GSUB 64
__global__ __launch_bounds__(256) void k_gram(
        const float* __restrict__ dist,
        const int*   __restrict__ qn,
        const int*   __restrict__ ao,
        const float* __restrict__ zeta,
        float*       __restrict__ gram) {   // [B][M][M]
    __shared__ float sg[GSUB][M_];          // 32 KB
    __shared__ float pz2[M_], pq[M_];
    const int b = blockIdx.y, ch = blockIdx.x, tid = threadIdx.x;
    if (tid < M_) {
        pq[tid] = (float)qn[b * M_ + tid];
        float z = zeta[ao[b * M_ + tid]];
        pz2[tid] = z * z;
    }
    float acc[8][8];
    #pragma unroll
    for (int i = 0; i < 8; ++i)
        #pragma unroll
        for (int j = 0; j < 8; ++j) acc[i][j] = 0.f;

    const int mi0 = (tid & 15) * 8;
    const int mj0 = (tid >> 4) * 8;
    const int CH_G = G_ / NCH;              // 256 g per block

    for (int s = 0; s < CH_G / GSUB; ++s) { // 4 sub-tiles of 64 g
        __syncthreads();
        {
            int m = tid & 127;
            float z2 = pz2[m], q = pq[m];
            #pragma unroll
            for (int r = tid >> 7; r < GSUB; r += 2) {
                float d = dist[((size_t)(b * G_ + ch * CH_G + s * GSUB + r)) * M_ + m];
                float e  = __expf(-z2 * d * d);
                float p1 = (q < 1.5f) ? 1.f : ((q < 2.5f) ? d : d * d);
                sg[r][m] = p1 * e;
            }
        }
        __syncthreads();
        #pragma unroll 4
        for (int g = 0; g < GSUB; ++g) {
            float av[8], bv[8];
            *(float4*)&av[0] = *(const float4*)&sg[g][mi0];
            *(float4*)&av[4] = *(const float4*)&sg[g][mi0 + 4];
            *(float4*)&bv[0] = *(const float4*)&sg[g][mj0];
            *(float4*)&bv[4] = *(const float4*)&sg[g][mj0 + 4];
            #pragma unroll
            for (int i = 0; i < 8; ++i)
                #pragma unroll
                for (int j = 0; j < 8; ++j)
                    acc[i][j] = fmaf(av[i], bv[j], acc[i][j]);
        }
    }
    float* gp = gram + (size_t)b * M_ * M_;
    #pragma unroll
    for (int i = 0; i < 8; ++i)
        #pragma unroll
        for (int j = 0; j < 8; ++j)
            atomicAdd(&gp[(mi0 + i) * M_ + (mj0 + j)], acc[i][j]);
}

// ---------------------------------------------------------------------------
// K1: per-(b,d) coefficient column sum-of-squares over m.
// ---------------------------------------------------------------------------
__global__ void k_cnorm(const int*   __restrict__ ao,
                        const float* __restrict__ table,
                        float*       __restrict__ cnorm2) {
    int b = blockIdx.y;
    int d = blockIdx.x * 256 + threadIdx.x;
    __shared__ int sao[M_];
    if (threadIdx.x < M_) sao[threadIdx.x] = ao[b * M_ + threadIdx.x];
    __syncthreads();
    float acc = 0.f;
    #pragma unroll 8
    for (int m = 0; m < M_; ++m) {
        float v = table[(size_t)sao[m] * D_ + d];
        acc += v * v;
    }
    cnorm2[b * D_ + d] = acc;
}

// ---------------------------------------------------------------------------
// K2: scale[b][d] = sqrt(Nel/D) / max(sqrt(u_d^T Gram u_d), EPS),
// u[m,d] = table[ao[m]][d] * rg[m] * rcn[d].  Gram quadratic form replaces
// the old materialize-mo + norm + rescale second pass entirely.
// ---------------------------------------------------------------------------
__global__ __launch_bounds__(256) void k_mosq(
        const float* __restrict__ gram,
        const int*   __restrict__ ao,
        const float* __restrict__ table,
        const float* __restrict__ cnorm2,
        const float* __restrict__ Nel,
        float*       __restrict__ scale) {
    __shared__ float su[M_][64];     // 32 KB
    __shared__ float sGq[32][M_];    // 16 KB
    __shared__ float prg[M_];
    __shared__ float sred[4][64];
    const int b = blockIdx.y, d0 = blockIdx.x * 64, tid = threadIdx.x;
    const float* gb = gram + (size_t)b * M_ * M_;
    if (tid < M_) {
        float gd = gb[tid * M_ + tid];
        prg[tid] = 1.f / (fmaxf(sqrtf(gd), EPS_) * GI15);
    }
    __syncthreads();
    const int dl = tid & 63, quad = tid >> 6;
    {
        float rcn = 1.f / fmaxf(sqrtf(cnorm2[b * D_ + d0 + dl]), EPS_);
        #pragma unroll 4
        for (int k = 0; k < 32; ++k) {
            int m = quad + 4 * k;
            su[m][dl] = table[(size_t)ao[b * M_ + m] * D_ + d0 + dl] * prg[m] * rcn;
        }
    }
    float acc = 0.f;
    for (int qt = 0; qt < 4; ++qt) {
        __syncthreads();
        for (int e = tid; e < 32 * M_; e += 256) {
            int mr = e >> 7, mc = e & 127;
            sGq[mr][mc] = gb[(qt * 32 + mr) * M_ + mc];
        }
        __syncthreads();
        #pragma unroll
        for (int mr8 = 0; mr8 < 8; ++mr8) {
            int mr = quad * 8 + mr8;
            float t0 = 0.f, t1 = 0.f, t2 = 0.f, t3 = 0.f;
            #pragma unroll 4
            for (int mc = 0; mc < M_; mc += 4) {
                t0 = fmaf(sGq[mr][mc],     su[mc][dl],     t0);
                t1 = fmaf(sGq[mr][mc + 1], su[mc + 1][dl], t1);
                t2 = fmaf(sGq[mr][mc + 2], su[mc + 2][dl], t2);
                t3 = fmaf(sGq[mr][mc + 3], su[mc + 3][dl], t3);
            }
            acc = fmaf(su[qt * 32 + mr][dl], (t0 + t1) + (t2 + t3), acc);
        }
    }
    sred[quad][dl] = acc;
    __syncthreads();
    if (quad == 0) {
        float mo2 = sred[0][dl] + sred[1][dl] + sred[2][dl] + sred[3][dl];
        scale[b * D_ + d0 + dl] =
            sqrtf(Nel[b] / (float)D_) / fmaxf(sqrtf(mo2), EPS_);
    }
}

// ---------------------------------------------------------------------------
// K3: fused GEMM, final outputs in one pass.  64g x 64d per block, K=128.
// B-tile = table[ao[m]][d] * rg[m] * (rcn[d]*scale[d]) shared by mo & l_mo.
// ---------------------------------------------------------------------------
#define TG   64
#define TD   64
#define KC   16
#define ASTR 68

__global__ __launch_bounds__(256) void k_gemm(
        const float* __restrict__ dist,
        const int*   __restrict__ qn,
        const int*   __restrict__ ao,
        const float* __restrict__ zeta,
        const float* __restrict__ table,
        const float* __restrict__ gram,
        const float* __restrict__ cnorm2,
        const float* __restrict__ scale,
        float*       __restrict__ out) {   // [2][B*G][D]
    __shared__ float sAg[KC * ASTR];
    __shared__ float sAl[KC * ASTR];
    __shared__ float sB [KC * ASTR];
    __shared__ float pm_z2[M_], pm_q[M_], pm_rg[M_];
    __shared__ int   pm_ao[M_];
    __shared__ float rs[TD];

    const int tid = threadIdx.x;
    const int b  = blockIdx.z;
    const int g0 = blockIdx.y * TG;
    const int d0 = blockIdx.x * TD;

    if (tid < 128) {
        int m = tid;
        float q = (float)qn[b * M_ + m];
        int   a = ao[b * M_ + m];
        float z = zeta[a];
        pm_q[m]  = q;
        pm_z2[m] = z * z;
        pm_ao[m] = a;
        float gn = sqrtf(gram[(size_t)b * M_ * M_ + m * M_ + m]);
        pm_rg[m] = 1.f / (fmaxf(gn, EPS_) * GI15);
    } else if (tid < 192) {
        int dl = tid - 128;
        rs[dl] = scale[b * D_ + d0 + dl] /
                 fmaxf(sqrtf(cnorm2[b * D_ + d0 + dl]), EPS_);
    }
    __syncthreads();

    const int ty = tid >> 4, tx = tid & 15;
    const int m_l = tid & 15, gsub = tid >> 4;
    const int dl_ = tid & 63, msub = tid >> 6;

    float accm[4][4], accl[4][4];
    #pragma unroll
    for (int i = 0; i < 4; ++i)
        #pragma unroll
        for (int j = 0; j < 4; ++j) { accm[i][j] = 0.f; accl[i][j] = 0.f; }

    #pragma unroll 1
    for (int kc = 0; kc < 8; ++kc) {
        {
            int m = kc * KC + m_l;
            float z2 = pm_z2[m], q = pm_q[m];
            float c4 = 4.f * z2 * z2;
            float c2 = 2.f * z2 * (2.f * q + 1.f);
            float c0 = q * (q - 1.f);
            #pragma unroll
            for (int p = 0; p < 4; ++p) {
                int g = p * 16 + gsub;
                float d  = dist[((size_t)b * G_ + g0 + g) * M_ + m];
                float d2 = d * d;
                float e  = __expf(-z2 * d2);
                float p1 = (q < 1.5f) ? 1.f : ((q < 2.5f) ? d : d2);
                float gto  = p1 * e;
                float poly = (c4 * d2 - c2) * d2 + c0;
                float lg   = (p1 / d2) * e * poly;
                sAg[m_l * ASTR + g] = gto;
                sAl[m_l * ASTR + g] = lg;
            }
        }
        #pragma unroll
        for (int p = 0; p < 4; ++p) {
            int mk = p * 4 + msub;
            int mm = kc * KC + mk;
            float v = table[(size_t)pm_ao[mm] * D_ + d0 + dl_];
            sB[mk * ASTR + dl_] = v * rs[dl_] * pm_rg[mm];
        }
        __syncthreads();
        #pragma unroll
        for (int k = 0; k < KC; ++k) {
            float4 ag = *(const float4*)&sAg[k * ASTR + ty * 4];
            float4 av = *(const float4*)&sAl[k * ASTR + ty * 4];
            float4 bv = *(const float4*)&sB [k * ASTR + tx * 4];
            float a_[4] = {ag.x, ag.y, ag.z, ag.w};
            float l_[4] = {av.x, av.y, av.z, av.w};
            float b_[4] = {bv.x, bv.y, bv.z, bv.w};
            #pragma unroll
            for (int i = 0; i < 4; ++i)
                #pragma unroll
                for (int j = 0; j < 4; ++j) {
                    accm[i][j] = fmaf(a_[i], b_[j], accm[i][j]);
                    accl[i][j] = fmaf(l_[i], b_[j], accl[i][j]);
                }
        }
        __syncthreads();
    }

    const size_t HALF = (size_t)B_ * G_ * D_;
    size_t base0 = ((size_t)b * G_ + g0 + ty * 4) * D_ + d0 + tx * 4;
    #pragma unroll
    for (int i = 0; i < 4; ++i) {
        float4 vm = make_float4(accm[i][0], accm[i][1], accm[i][2], accm[i][3]);
        float4 vl = make_float4(accl[i][0], accl[i][1], accl[i][2], accl[i][3]);
        *(float4*)&out[base0 + (size_t)i * D_]        = vm;
        *(float4*)&out[HALF + base0 + (size_t)i * D_] = vl;
    }
}

// ---------------------------------------------------------------------------
extern "C" void kernel_launch(void* const* d_in, const int* in_sizes, int n_in,
                              void* d_out, int out_size, void* d_ws, size_t ws_size,
                              hipStream_t stream) {
    const float* dist  = (const float*)d_in[0];
    const int*   qn    = (const int*)  d_in[1];
    const int*   ao    = (const int*)  d_in[2];
    const float* Nel   = (const float*)d_in[3];
    const float* table = (const float*)d_in[4];
    const float* zeta  = (const float*)d_in[5];
    float* out = (float*)d_out;
    float* ws  = (float*)d_ws;

    float* gram   = ws;                         // [B][M][M] = 262144 floats
    float* cnorm2 = ws + 262144;                // [B][D]    = 12288
    float* scale  = ws + 262144 + 12288;        // [B][D]    = 12288

    hipMemsetAsync(gram, 0, (size_t)262144 * sizeof(float), stream);

    k_gram<<<dim3(NCH, B_), 256, 0, stream>>>(dist, qn, ao, zeta, gram);
    k_cnorm<<<dim3(3, B_), 256, 0, stream>>>(ao, table, cnorm2);
    k_mosq<<<dim3(D_ / 64, B_), 256, 0, stream>>>(gram, ao, table, cnorm2, Nel, scale);
    k_gemm<<<dim3(D_ / TD, G_ / TG, B_), 256, 0, stream>>>(
        dist, qn, ao, zeta, table, gram, cnorm2, scale, out);
}

// Round 6
// 655.631 us; speedup vs baseline: 1.4292x; 1.4292x over previous
//
#include <hip/hip_runtime.h>
#include <hip/hip_bf16.h>
#include <math.h>

#define B_    16
#define G_    4096
#define M_    128
#define D_    768
#define GI15  0.16431676725154983f   // 0.3^1.5
#define EPS_  1e-12f

typedef __attribute__((ext_vector_type(8))) short short8v;
typedef __attribute__((ext_vector_type(4))) float f32x4;
typedef unsigned short ushort_t;
typedef unsigned int   uint_t;

__device__ __forceinline__ ushort_t f2bf(float f) {   // RNE fp32->bf16 (finite)
    uint_t u = __float_as_uint(f);
    u += 0x7FFFu + ((u >> 16) & 1u);
    return (ushort_t)(u >> 16);
}
__device__ __forceinline__ float bf2f(ushort_t h) {
    return __uint_as_float(((uint_t)h) << 16);
}

// ---------------------------------------------------------------------------
// K0a: partial Gram matrices (NO atomics).  part[ch][b][128*128] lives in the
// (later overwritten) d_out buffer (67 MB < 402 MB, always in-bounds).
// ---------------------------------------------------------------------------
__global__ __launch_bounds__(256) void k_gram_part(
        const float* __restrict__ dist,
        const int*   __restrict__ qn,
        const int*   __restrict__ ao,
        const float* __restrict__ zeta,
        float*       __restrict__ part) {
    __shared__ float sg[64][M_];          // 32 KB
    __shared__ float pz2[M_], pq[M_];
    const int b = blockIdx.y, ch = blockIdx.x, tid = threadIdx.x;
    if (tid < M_) {
        pq[tid] = (float)qn[b * M_ + tid];
        float z = zeta[ao[b * M_ + tid]];
        pz2[tid] = z * z;
    }
    __syncthreads();
    {
        int m = tid & 127;
        float z2 = pz2[m], q = pq[m];
        for (int r = tid >> 7; r < 64; r += 2) {
            float d = dist[((size_t)(b * G_ + ch * 64 + r)) * M_ + m];
            float e  = __expf(-z2 * d * d);
            float p1 = (q < 1.5f) ? 1.f : ((q < 2.5f) ? d : d * d);
            sg[r][m] = p1 * e;
        }
    }
    __syncthreads();
    const int mi0 = (tid >> 4) * 8;
    const int mj0 = (tid & 15) * 8;
    float acc[8][8];
    #pragma unroll
    for (int i = 0; i < 8; ++i)
        #pragma unroll
        for (int j = 0; j < 8; ++j) acc[i][j] = 0.f;
    #pragma unroll 2
    for (int g = 0; g < 64; ++g) {
        float av[8], bv[8];
        *(float4*)&av[0] = *(const float4*)&sg[g][mi0];
        *(float4*)&av[4] = *(const float4*)&sg[g][mi0 + 4];
        *(float4*)&bv[0] = *(const float4*)&sg[g][mj0];
        *(float4*)&bv[4] = *(const float4*)&sg[g][mj0 + 4];
        #pragma unroll
        for (int i = 0; i < 8; ++i)
            #pragma unroll
            for (int j = 0; j < 8; ++j)
                acc[i][j] = fmaf(av[i], bv[j], acc[i][j]);
    }
    float* pp = part + ((size_t)(ch * B_ + b)) * (M_ * M_);
    #pragma unroll
    for (int i = 0; i < 8; ++i) {
        *(float4*)&pp[(mi0 + i) * M_ + mj0]     = make_float4(acc[i][0], acc[i][1], acc[i][2], acc[i][3]);
        *(float4*)&pp[(mi0 + i) * M_ + mj0 + 4] = make_float4(acc[i][4], acc[i][5], acc[i][6], acc[i][7]);
    }
}

// K0b: reduce 64 partials -> gram[b][128][128]
__global__ void k_gram_red(const float* __restrict__ part,
                           float*       __restrict__ gram) {
    int idx = blockIdx.x * 256 + threadIdx.x;     // < 262144
    float s = 0.f;
    #pragma unroll 8
    for (int ch = 0; ch < 64; ++ch)
        s += part[(size_t)ch * (B_ * M_ * M_) + idx];
    gram[idx] = s;
}

// ---------------------------------------------------------------------------
// K1: per-(b,d): coeff col-norm + Gram quadratic form -> cf[b][d] = rcn*scale.
// (No bf16 export: keeps ws usage ~1.1 MB, within the proven bound.)
// ---------------------------------------------------------------------------
__global__ __launch_bounds__(256) void k_mosq(
        const float* __restrict__ gram,
        const int*   __restrict__ ao,
        const float* __restrict__ table,
        const float* __restrict__ Nel,
        float*       __restrict__ cf) {
    __shared__ float sv[M_][64];     // 32 KB
    __shared__ float sGq[32][M_];    // 16 KB
    __shared__ float prg[M_];
    __shared__ float sred[4][64];
    __shared__ float srcn[64];
    const int b = blockIdx.y, d0 = blockIdx.x * 64, tid = threadIdx.x;
    const int dl = tid & 63, quad = tid >> 6;
    const float* gb = gram + (size_t)b * M_ * M_;
    if (tid < M_)
        prg[tid] = 1.f / (fmaxf(sqrtf(gb[tid * M_ + tid]), EPS_) * GI15);
    #pragma unroll 4
    for (int k = 0; k < 32; ++k) {
        int m = quad * 32 + k;
        sv[m][dl] = table[(size_t)ao[b * M_ + m] * D_ + d0 + dl];
    }
    __syncthreads();
    {
        float cs = 0.f;
        #pragma unroll 4
        for (int k = 0; k < 32; ++k) { float v = sv[quad * 32 + k][dl]; cs = fmaf(v, v, cs); }
        sred[quad][dl] = cs;
    }
    __syncthreads();
    if (quad == 0)
        srcn[dl] = 1.f / fmaxf(sqrtf(sred[0][dl] + sred[1][dl] + sred[2][dl] + sred[3][dl]), EPS_);
    #pragma unroll 4
    for (int k = 0; k < 32; ++k) { int m = quad * 32 + k; sv[m][dl] *= prg[m]; }
    __syncthreads();
    float acc = 0.f;
    for (int qt = 0; qt < 4; ++qt) {
        for (int e = tid; e < 32 * M_; e += 256)
            sGq[e >> 7][e & 127] = gb[(qt * 32 + (e >> 7)) * M_ + (e & 127)];
        __syncthreads();
        #pragma unroll
        for (int mr8 = 0; mr8 < 8; ++mr8) {
            int mr = quad * 8 + mr8;
            float t0 = 0.f, t1 = 0.f, t2 = 0.f, t3 = 0.f;
            #pragma unroll 4
            for (int mc = 0; mc < M_; mc += 4) {
                t0 = fmaf(sGq[mr][mc],     sv[mc][dl],     t0);
                t1 = fmaf(sGq[mr][mc + 1], sv[mc + 1][dl], t1);
                t2 = fmaf(sGq[mr][mc + 2], sv[mc + 2][dl], t2);
                t3 = fmaf(sGq[mr][mc + 3], sv[mc + 3][dl], t3);
            }
            acc = fmaf(sv[qt * 32 + mr][dl], (t0 + t1) + (t2 + t3), acc);
        }
        __syncthreads();
    }
    sred[quad][dl] = acc;
    __syncthreads();
    if (quad == 0) {
        float qf  = fmaxf(sred[0][dl] + sred[1][dl] + sred[2][dl] + sred[3][dl], 0.f);
        float rcn = srcn[dl];
        float mo  = rcn * sqrtf(qf);
        cf[b * D_ + d0 + dl] =
            sqrtf(Nel[b] / (float)D_) / fmaxf(mo, EPS_) * rcn;
    }
}

// ---------------------------------------------------------------------------
// K2: MFMA GEMM.  64g x 64d per block, 4 waves, K=128 in 4 steps of 32.
// A (gto & l_gto) generated on the fly as split bf16 into LDS; B' built
// in-prologue from table * prg[m] * cf[d], split bf16, XOR-swizzled LDS.
// ---------------------------------------------------------------------------
__global__ __launch_bounds__(256, 3) void k_gemm(
        const float* __restrict__ dist,
        const int*   __restrict__ qn,
        const int*   __restrict__ ao,
        const float* __restrict__ zeta,
        const float* __restrict__ table,
        const float* __restrict__ gram,
        const float* __restrict__ cf,
        float*       __restrict__ out) {
    __shared__ ushort_t sA0[2048], sA1[2048], sA2[2048], sA3[2048]; // [64g][32k]
    __shared__ ushort_t sBh[8192], sBl[8192];                       // [64d][128k] swizzled
    __shared__ float pz2[M_], pq[M_], prg_s[M_];
    __shared__ int   pm_ao[M_];
    __shared__ float scf_s[64];
    const int tid = threadIdx.x;
    const int b  = blockIdx.z;
    const int g0 = blockIdx.y * 64;
    const int d0 = blockIdx.x * 64;
    if (tid < M_) {
        pq[tid] = (float)qn[b * M_ + tid];
        int a = ao[b * M_ + tid];
        pm_ao[tid] = a;
        float z = zeta[a];
        pz2[tid] = z * z;
        prg_s[tid] = 1.f / (fmaxf(sqrtf(gram[(size_t)b * M_ * M_ + tid * (M_ + 1)]), EPS_) * GI15);
    } else if (tid < M_ + 64) {
        scf_s[tid - M_] = cf[b * D_ + d0 + (tid - M_)];
    }
    __syncthreads();

    // ---- stage B': split bf16, swizzled write ----
    {
        const int dl_ = tid & 63, quad = tid >> 6;
        float cfv = scf_s[dl_];
        #pragma unroll
        for (int mq = 0; mq < 4; ++mq) {
            int m0 = quad * 32 + mq * 8;
            ushort_t h[8], l[8];
            #pragma unroll
            for (int r = 0; r < 8; ++r) {
                int m = m0 + r;
                float v = table[(size_t)pm_ao[m] * D_ + d0 + dl_] * prg_s[m] * cfv;
                h[r] = f2bf(v);
                l[r] = f2bf(v - bf2f(h[r]));
            }
            int tgt = dl_ * 256 + ((m0 * 2) ^ ((dl_ & 7) << 4));
            *(uint4*)((char*)sBh + tgt) = *(const uint4*)&h[0];
            *(uint4*)((char*)sBl + tgt) = *(const uint4*)&l[0];
        }
    }
    __syncthreads();

    const int lane = tid & 63, w = tid >> 6;
    const int lrow = lane & 15, lk8 = (lane >> 4) * 8;
    f32x4 accm[4], accl[4];
    #pragma unroll
    for (int t = 0; t < 4; ++t) {
        accm[t] = (f32x4){0.f, 0.f, 0.f, 0.f};
        accl[t] = (f32x4){0.f, 0.f, 0.f, 0.f};
    }

    const int ml  = tid & 31;   // k (m) within subtile
    const int gof = tid >> 5;   // 0..7

    for (int kc = 0; kc < 4; ++kc) {
        // ---- generate A subtile: 64 g x 32 k, split bf16 ----
        {
            int m = kc * 32 + ml;
            float z2 = pz2[m], q = pq[m];
            float c4 = 4.f * z2 * z2;
            float c2 = 2.f * z2 * (2.f * q + 1.f);
            float c0 = q * (q - 1.f);
            #pragma unroll
            for (int pass = 0; pass < 8; ++pass) {
                int g = pass * 8 + gof;
                float d  = dist[((size_t)(b * G_ + g0 + g)) * M_ + m];
                float d2 = d * d;
                float e  = __expf(-z2 * d2);
                float p1 = (q < 1.5f) ? 1.f : ((q < 2.5f) ? d : d2);
                float gto  = p1 * e;
                float poly = fmaf(fmaf(c4, d2, -c2), d2, c0);
                float lg   = __fdividef(p1, d2) * e * poly;
                int o = g * 32 + ml;
                ushort_t gh = f2bf(gto);
                sA0[o] = gh;
                sA1[o] = f2bf(gto - bf2f(gh));
                ushort_t lh = f2bf(lg);
                sA2[o] = lh;
                sA3[o] = f2bf(lg - bf2f(lh));
            }
        }
        __syncthreads();
        // ---- MFMA ----
        {
            int oa = (w * 16 + lrow) * 32 + lk8;
            short8v agh = *(const short8v*)&sA0[oa];
            short8v agl = *(const short8v*)&sA1[oa];
            short8v alh = *(const short8v*)&sA2[oa];
            short8v all_= *(const short8v*)&sA3[oa];
            int kk2 = (kc * 32 + lk8) * 2;
            #pragma unroll
            for (int dt = 0; dt < 4; ++dt) {
                int dr = dt * 16 + lrow;
                int off = dr * 256 + (kk2 ^ ((dr & 7) << 4));
                short8v bh = *(const short8v*)((const char*)sBh + off);
                short8v bl = *(const short8v*)((const char*)sBl + off);
                accm[dt] = __builtin_amdgcn_mfma_f32_16x16x32_bf16(agh, bh, accm[dt], 0, 0, 0);
                accm[dt] = __builtin_amdgcn_mfma_f32_16x16x32_bf16(agh, bl, accm[dt], 0, 0, 0);
                accm[dt] = __builtin_amdgcn_mfma_f32_16x16x32_bf16(agl, bh, accm[dt], 0, 0, 0);
                accl[dt] = __builtin_amdgcn_mfma_f32_16x16x32_bf16(alh, bh, accl[dt], 0, 0, 0);
                accl[dt] = __builtin_amdgcn_mfma_f32_16x16x32_bf16(alh, bl, accl[dt], 0, 0, 0);
                accl[dt] = __builtin_amdgcn_mfma_f32_16x16x32_bf16(all_, bh, accl[dt], 0, 0, 0);
            }
        }
        __syncthreads();
    }

    // ---- store: C/D layout col=lane&15 (d), row=(lane>>4)*4+reg (g) ----
    const size_t HALF = (size_t)B_ * G_ * D_;
    const int grow = g0 + w * 16 + (lane >> 4) * 4;
    #pragma unroll
    for (int dt = 0; dt < 4; ++dt) {
        int dcol = d0 + dt * 16 + lrow;
        #pragma unroll
        for (int r = 0; r < 4; ++r) {
            size_t off = ((size_t)(b * G_) + grow + r) * D_ + dcol;
            out[off]        = accm[dt][r];
            out[HALF + off] = accl[dt][r];
        }
    }
}

// ---------------------------------------------------------------------------
extern "C" void kernel_launch(void* const* d_in, const int* in_sizes, int n_in,
                              void* d_out, int out_size, void* d_ws, size_t ws_size,
                              hipStream_t stream) {
    const float* dist  = (const float*)d_in[0];
    const int*   qn    = (const int*)  d_in[1];
    const int*   ao    = (const int*)  d_in[2];
    const float* Nel   = (const float*)d_in[3];
    const float* table = (const float*)d_in[4];
    const float* zeta  = (const float*)d_in[5];
    float* out = (float*)d_out;
    float* ws  = (float*)d_ws;

    float* gram = ws;              // 262144 floats (1 MB)
    float* cf   = ws + 262144;     // 12288 floats (48 KB) -> total 1.098 MB
    float* part = out;             // [64][16][16384] = 67 MB scratch inside d_out

    k_gram_part<<<dim3(64, B_), 256, 0, stream>>>(dist, qn, ao, zeta, part);
    k_gram_red<<<1024, 256, 0, stream>>>(part, gram);
    k_mosq<<<dim3(D_ / 64, B_), 256, 0, stream>>>(gram, ao, table, Nel, cf);
    k_gemm<<<dim3(D_ / 64, G_ / 64, B_), 256, 0, stream>>>(
        dist, qn, ao, zeta, table, gram, cf, out);
}

// Round 7
// 590.465 us; speedup vs baseline: 1.5870x; 1.1104x over previous
//
#include <hip/hip_runtime.h>
#include <hip/hip_bf16.h>
#include <math.h>

#define B_    16
#define G_    4096
#define M_    128
#define D_    768
#define GI15  0.16431676725154983f   // 0.3^1.5
#define EPS_  1e-12f

typedef __attribute__((ext_vector_type(8))) short short8v;
typedef __attribute__((ext_vector_type(4))) float f32x4;
typedef unsigned short ushort_t;
typedef unsigned int   uint_t;

__device__ __forceinline__ ushort_t f2bf(float f) {   // RNE fp32->bf16 (finite)
    uint_t u = __float_as_uint(f);
    u += 0x7FFFu + ((u >> 16) & 1u);
    return (ushort_t)(u >> 16);
}
__device__ __forceinline__ float bf2f(ushort_t h) {
    return __uint_as_float(((uint_t)h) << 16);
}

// ---------------------------------------------------------------------------
// K0a: partial Gram matrices (NO atomics).  part[ch][b][128*128] in d_out
// scratch (67 MB < 402 MB; fully overwritten by k_gemm afterwards).
// ---------------------------------------------------------------------------
__global__ __launch_bounds__(256) void k_gram_part(
        const float* __restrict__ dist,
        const int*   __restrict__ qn,
        const int*   __restrict__ ao,
        const float* __restrict__ zeta,
        float*       __restrict__ part) {
    __shared__ float sg[64][M_];          // 32 KB
    __shared__ float pz2[M_], pq[M_];
    const int b = blockIdx.y, ch = blockIdx.x, tid = threadIdx.x;
    if (tid < M_) {
        pq[tid] = (float)qn[b * M_ + tid];
        float z = zeta[ao[b * M_ + tid]];
        pz2[tid] = z * z;
    }
    __syncthreads();
    {
        int m = tid & 127;
        float z2 = pz2[m], q = pq[m];
        for (int r = tid >> 7; r < 64; r += 2) {
            float d = dist[((size_t)(b * G_ + ch * 64 + r)) * M_ + m];
            float e  = __expf(-z2 * d * d);
            float p1 = (q < 1.5f) ? 1.f : ((q < 2.5f) ? d : d * d);
            sg[r][m] = p1 * e;
        }
    }
    __syncthreads();
    const int mi0 = (tid >> 4) * 8;
    const int mj0 = (tid & 15) * 8;
    float acc[8][8];
    #pragma unroll
    for (int i = 0; i < 8; ++i)
        #pragma unroll
        for (int j = 0; j < 8; ++j) acc[i][j] = 0.f;
    #pragma unroll 2
    for (int g = 0; g < 64; ++g) {
        float av[8], bv[8];
        *(float4*)&av[0] = *(const float4*)&sg[g][mi0];
        *(float4*)&av[4] = *(const float4*)&sg[g][mi0 + 4];
        *(float4*)&bv[0] = *(const float4*)&sg[g][mj0];
        *(float4*)&bv[4] = *(const float4*)&sg[g][mj0 + 4];
        #pragma unroll
        for (int i = 0; i < 8; ++i)
            #pragma unroll
            for (int j = 0; j < 8; ++j)
                acc[i][j] = fmaf(av[i], bv[j], acc[i][j]);
    }
    float* pp = part + ((size_t)(ch * B_ + b)) * (M_ * M_);
    #pragma unroll
    for (int i = 0; i < 8; ++i) {
        *(float4*)&pp[(mi0 + i) * M_ + mj0]     = make_float4(acc[i][0], acc[i][1], acc[i][2], acc[i][3]);
        *(float4*)&pp[(mi0 + i) * M_ + mj0 + 4] = make_float4(acc[i][4], acc[i][5], acc[i][6], acc[i][7]);
    }
}

// K0b: reduce 64 partials -> gram[b][128][128]
__global__ void k_gram_red(const float* __restrict__ part,
                           float*       __restrict__ gram) {
    int idx = blockIdx.x * 256 + threadIdx.x;     // < 262144
    float s = 0.f;
    #pragma unroll 8
    for (int ch = 0; ch < 64; ++ch)
        s += part[(size_t)ch * (B_ * M_ * M_) + idx];
    gram[idx] = s;
}

// ---------------------------------------------------------------------------
// K1: per-(b,d-tile): coeff col-norm + Gram quadratic form -> final column
// factor; exports pre-split bf16 B' = table*prg[m]*rcn*scale as
// Bsplit[b][d][m] hi/lo, ready for k_gemm's swizzled LDS copy.
// ---------------------------------------------------------------------------
__global__ __launch_bounds__(256) void k_mosq(
        const float* __restrict__ gram,
        const int*   __restrict__ ao,
        const float* __restrict__ table,
        const float* __restrict__ Nel,
        ushort_t*    __restrict__ bhiG,
        ushort_t*    __restrict__ bloG) {
    __shared__ float sv[M_][64];     // 32 KB
    __shared__ float sGq[32][M_];    // 16 KB
    __shared__ float prg[M_];
    __shared__ float sred[4][64];
    __shared__ float srcn[64], scf[64];
    const int b = blockIdx.y, d0 = blockIdx.x * 64, tid = threadIdx.x;
    const int dl = tid & 63, quad = tid >> 6;
    const float* gb = gram + (size_t)b * M_ * M_;
    if (tid < M_)
        prg[tid] = 1.f / (fmaxf(sqrtf(gb[tid * M_ + tid]), EPS_) * GI15);
    #pragma unroll 4
    for (int k = 0; k < 32; ++k) {
        int m = quad * 32 + k;
        sv[m][dl] = table[(size_t)ao[b * M_ + m] * D_ + d0 + dl];
    }
    __syncthreads();
    {
        float cs = 0.f;
        #pragma unroll 4
        for (int k = 0; k < 32; ++k) { float v = sv[quad * 32 + k][dl]; cs = fmaf(v, v, cs); }
        sred[quad][dl] = cs;
    }
    __syncthreads();
    if (quad == 0)
        srcn[dl] = 1.f / fmaxf(sqrtf(sred[0][dl] + sred[1][dl] + sred[2][dl] + sred[3][dl]), EPS_);
    #pragma unroll 4
    for (int k = 0; k < 32; ++k) { int m = quad * 32 + k; sv[m][dl] *= prg[m]; }
    __syncthreads();
    float acc = 0.f;
    for (int qt = 0; qt < 4; ++qt) {
        for (int e = tid; e < 32 * M_; e += 256)
            sGq[e >> 7][e & 127] = gb[(qt * 32 + (e >> 7)) * M_ + (e & 127)];
        __syncthreads();
        #pragma unroll
        for (int mr8 = 0; mr8 < 8; ++mr8) {
            int mr = quad * 8 + mr8;
            float t0 = 0.f, t1 = 0.f, t2 = 0.f, t3 = 0.f;
            #pragma unroll 4
            for (int mc = 0; mc < M_; mc += 4) {
                t0 = fmaf(sGq[mr][mc],     sv[mc][dl],     t0);
                t1 = fmaf(sGq[mr][mc + 1], sv[mc + 1][dl], t1);
                t2 = fmaf(sGq[mr][mc + 2], sv[mc + 2][dl], t2);
                t3 = fmaf(sGq[mr][mc + 3], sv[mc + 3][dl], t3);
            }
            acc = fmaf(sv[qt * 32 + mr][dl], (t0 + t1) + (t2 + t3), acc);
        }
        __syncthreads();
    }
    sred[quad][dl] = acc;
    __syncthreads();
    if (quad == 0) {
        float qf  = fmaxf(sred[0][dl] + sred[1][dl] + sred[2][dl] + sred[3][dl], 0.f);
        float rcn = srcn[dl];
        float mo  = rcn * sqrtf(qf);
        scf[dl] = sqrtf(Nel[b] / (float)D_) / fmaxf(mo, EPS_) * rcn;
    }
    __syncthreads();
    {
        float cfv = scf[dl];
        ushort_t* bh = bhiG + ((size_t)b * D_ + d0 + dl) * M_;
        ushort_t* bl = bloG + ((size_t)b * D_ + d0 + dl) * M_;
        #pragma unroll
        for (int mq = 0; mq < 4; ++mq) {
            int mb = quad * 32 + mq * 8;
            ushort_t h[8], l[8];
            #pragma unroll
            for (int r = 0; r < 8; ++r) {
                float v = sv[mb + r][dl] * cfv;
                h[r] = f2bf(v);
                l[r] = f2bf(v - bf2f(h[r]));
            }
            *(uint4*)&bh[mb] = *(const uint4*)&h[0];
            *(uint4*)&bl[mb] = *(const uint4*)&l[0];
        }
    }
}

// ---------------------------------------------------------------------------
// K2: MFMA GEMM.  64g x 128d per block, 512 threads = 8 waves (2 d-halves x
// 4 g-subtiles).  K=128 in 4 steps of 32.  A (gto & l_gto) generated on the
// fly as split bf16 into LDS (shared by ALL 128 d-cols -> 6x less redundant
// than TD=64); B' copied from precomputed global split (swizzled).
// LDS = 16 KB (A) + 64 KB (B) = 80 KB -> 2 blocks/CU; VGPR capped at 128.
// ---------------------------------------------------------------------------
__global__ __launch_bounds__(512, 4) void k_gemm(
        const float* __restrict__ dist,
        const int*   __restrict__ qn,
        const int*   __restrict__ ao,
        const float* __restrict__ zeta,
        const ushort_t* __restrict__ bhiG,
        const ushort_t* __restrict__ bloG,
        float*       __restrict__ out) {
    __shared__ ushort_t sA0[2048], sA1[2048], sA2[2048], sA3[2048]; // [64g][32k]
    __shared__ ushort_t sBh[16384], sBl[16384];                     // [128d][128k] swizzled
    const int tid = threadIdx.x;
    const int b  = blockIdx.z;
    const int g0 = blockIdx.y * 64;
    const int d0 = blockIdx.x * 128;

    // ---- stage B' (linear global read, swizzled LDS write) ----
    {
        const uint_t* gh = (const uint_t*)(bhiG + ((size_t)b * D_ + d0) * M_);
        const uint_t* gl = (const uint_t*)(bloG + ((size_t)b * D_ + d0) * M_);
        #pragma unroll
        for (int p = 0; p < 16; ++p) {
            int j = p * 512 + tid;                 // dword index < 8192
            int drow   = j >> 6;                   // 0..127 (64 dwords/row)
            int inrow4 = (j & 63) << 2;
            int tgt = drow * 256 + (inrow4 ^ ((drow & 7) << 4));
            *(uint_t*)((char*)sBh + tgt) = gh[j];
            *(uint_t*)((char*)sBl + tgt) = gl[j];
        }
    }

    // ---- preload per-thread A-gen params (m = kc*32 + ml) ----
    const int ml  = tid & 31;
    const int gof = tid >> 5;                      // 0..15
    float q4[4], z24[4];
    #pragma unroll
    for (int kc = 0; kc < 4; ++kc) {
        int m = kc * 32 + ml;
        q4[kc]  = (float)qn[b * M_ + m];
        float z = zeta[ao[b * M_ + m]];
        z24[kc] = z * z;
    }

    const int lane = tid & 63, w = tid >> 6;       // 8 waves
    const int gsub  = (w & 3) * 16;                // g-subtile of this wave
    const int dhalf = (w >> 2) * 64;               // d-half of this wave
    const int lrow = lane & 15, lk8 = (lane >> 4) * 8;
    f32x4 accm[4], accl[4];
    #pragma unroll
    for (int t = 0; t < 4; ++t) {
        accm[t] = (f32x4){0.f, 0.f, 0.f, 0.f};
        accl[t] = (f32x4){0.f, 0.f, 0.f, 0.f};
    }
    __syncthreads();

    for (int kc = 0; kc < 4; ++kc) {
        // ---- generate A subtile: 64 g x 32 k, split bf16 ----
        {
            int m = kc * 32 + ml;
            float z2 = z24[kc], q = q4[kc];
            float c4 = 4.f * z2 * z2;
            float c2 = 2.f * z2 * (2.f * q + 1.f);
            float c0 = q * (q - 1.f);
            #pragma unroll
            for (int pass = 0; pass < 4; ++pass) {
                int g = pass * 16 + gof;
                float d  = dist[((size_t)(b * G_ + g0 + g)) * M_ + m];
                float d2 = d * d;
                float e  = __expf(-z2 * d2);
                float p1 = (q < 1.5f) ? 1.f : ((q < 2.5f) ? d : d2);
                float gto  = p1 * e;
                float poly = fmaf(fmaf(c4, d2, -c2), d2, c0);
                float lg   = __fdividef(p1, d2) * e * poly;
                int o = g * 32 + ml;
                ushort_t gh = f2bf(gto);
                sA0[o] = gh;
                sA1[o] = f2bf(gto - bf2f(gh));
                ushort_t lh = f2bf(lg);
                sA2[o] = lh;
                sA3[o] = f2bf(lg - bf2f(lh));
            }
        }
        __syncthreads();
        // ---- MFMA: this wave: 16g x 64d over K=32 ----
        {
            int oa = (gsub + lrow) * 32 + lk8;
            short8v agh = *(const short8v*)&sA0[oa];
            short8v agl = *(const short8v*)&sA1[oa];
            short8v alh = *(const short8v*)&sA2[oa];
            short8v all_= *(const short8v*)&sA3[oa];
            int kk2 = (kc * 32 + lk8) * 2;
            #pragma unroll
            for (int dt = 0; dt < 4; ++dt) {
                int dr = dhalf + dt * 16 + lrow;
                int off = dr * 256 + (kk2 ^ ((dr & 7) << 4));
                short8v bh = *(const short8v*)((const char*)sBh + off);
                short8v bl = *(const short8v*)((const char*)sBl + off);
                accm[dt] = __builtin_amdgcn_mfma_f32_16x16x32_bf16(agh, bh, accm[dt], 0, 0, 0);
                accm[dt] = __builtin_amdgcn_mfma_f32_16x16x32_bf16(agh, bl, accm[dt], 0, 0, 0);
                accm[dt] = __builtin_amdgcn_mfma_f32_16x16x32_bf16(agl, bh, accm[dt], 0, 0, 0);
                accl[dt] = __builtin_amdgcn_mfma_f32_16x16x32_bf16(alh, bh, accl[dt], 0, 0, 0);
                accl[dt] = __builtin_amdgcn_mfma_f32_16x16x32_bf16(alh, bl, accl[dt], 0, 0, 0);
                accl[dt] = __builtin_amdgcn_mfma_f32_16x16x32_bf16(all_, bh, accl[dt], 0, 0, 0);
            }
        }
        __syncthreads();
    }

    // ---- store: C/D layout col=lane&15 (d), row=(lane>>4)*4+reg (g) ----
    const size_t HALF = (size_t)B_ * G_ * D_;
    const int grow = g0 + gsub + (lane >> 4) * 4;
    #pragma unroll
    for (int dt = 0; dt < 4; ++dt) {
        int dcol = d0 + dhalf + dt * 16 + lrow;
        #pragma unroll
        for (int r = 0; r < 4; ++r) {
            size_t off = ((size_t)(b * G_) + grow + r) * D_ + dcol;
            out[off]        = accm[dt][r];
            out[HALF + off] = accl[dt][r];
        }
    }
}

// ---------------------------------------------------------------------------
extern "C" void kernel_launch(void* const* d_in, const int* in_sizes, int n_in,
                              void* d_out, int out_size, void* d_ws, size_t ws_size,
                              hipStream_t stream) {
    const float* dist  = (const float*)d_in[0];
    const int*   qn    = (const int*)  d_in[1];
    const int*   ao    = (const int*)  d_in[2];
    const float* Nel   = (const float*)d_in[3];
    const float* table = (const float*)d_in[4];
    const float* zeta  = (const float*)d_in[5];
    float* out = (float*)d_out;
    float* ws  = (float*)d_ws;

    float*    gram = ws;                         // 1 MB
    ushort_t* bhi  = (ushort_t*)(ws + 262144);   // 3 MB
    ushort_t* blo  = (ushort_t*)(ws + 262144 + 786432);  // 3 MB (ws total 7 MB)
    float*    part = out;                        // 67 MB scratch inside d_out

    k_gram_part<<<dim3(64, B_), 256, 0, stream>>>(dist, qn, ao, zeta, part);
    k_gram_red<<<1024, 256, 0, stream>>>(part, gram);
    k_mosq<<<dim3(D_ / 64, B_), 256, 0, stream>>>(gram, ao, table, Nel, bhi, blo);
    k_gemm<<<dim3(D_ / 128, G_ / 64, B_), 512, 0, stream>>>(
        dist, qn, ao, zeta, bhi, blo, out);
}